// Round 1
// baseline (272.141 us; speedup 1.0000x reference)
//
#include <hip/hip_runtime.h>
#include <math.h>

#define D 256
#define NU 127
#define TWO_NU 254

// log(I_NU(x) * exp(-x)) via Miller's downward recurrence, carried in LINEAR
// space with branchless periodic rescaling. Mathematically identical to the
// reference's log-space recurrence (same truncation at i=254), cheap on VALU.
__device__ __forceinline__ float log_ive_nu(float x) {
  float xc = fmaxf(x, 1e-10f);
  float rx = 1.0f / xc;
  float p = 1.0f, pp = 0.0f, k = 0.0f;
  float fi2 = 2.0f * (float)TWO_NU;  // 2*i
  float pnu = 1.0f, knu = 0.0f;
  #pragma unroll 2
  for (int i = TWO_NU; i >= 1; --i) {
    float pn = fmaf(fi2 * rx, p, pp);
    fi2 -= 2.0f;
    pp = p;
    p = pn;
    if (i == NU + 1) { pnu = pn; knu = k; }  // p_{127}, scale at capture
    bool big = p > 1e20f;
    float s = big ? 1e-20f : 1.0f;
    p *= s;
    pp *= s;
    k += big ? 1.0f : 0.0f;
  }
  // log(p_127 / p_0), undoing the rescales
  float lratio = logf(pnu) - logf(p) + (knu - k) * 46.0517019f;  // ln(1e20)

  // log(i0e(x)) via Abramowitz & Stegun 9.8.1 / 9.8.2 (|err| < 2e-7)
  float li0e;
  if (xc >= 3.75f) {
    float t = 3.75f / xc;
    float P = 0.39894228f + t * (0.01328592f + t * (0.00225319f + t * (-0.00157565f +
              t * (0.00916281f + t * (-0.02057706f + t * (0.02635537f + t * (-0.01647633f +
              t * 0.00392377f)))))));
    li0e = logf(P) - 0.5f * logf(xc);
  } else {
    float u = xc * (1.0f / 3.75f);
    u = u * u;
    float P = 1.0f + u * (3.5156229f + u * (3.0899424f + u * (1.2067492f +
              u * (0.2659732f + u * (0.0360768f + u * 0.0045813f)))));
    li0e = logf(P) - xc;
  }
  return li0e + lratio;
}

// One block per class: deterministic per-class count+sum, blend, kappa, logc,
// and kappa*mu stored TRANSPOSED (kmuT[d*C + c]) for coalesced reads in k_main.
__global__ __launch_bounds__(256) void k_stats(
    const float* __restrict__ F, const float* __restrict__ Ave,
    const float* __restrict__ Amount, const int* __restrict__ labels,
    int N, int C, float* __restrict__ kmuT, float* __restrict__ logc) {
  const int c = blockIdx.x;
  const int d = threadIdx.x;  // feature dim, 0..255
  __shared__ int slab[1024];
  __shared__ float red[256];
  float acc = 0.0f;
  int cnt = 0;
  for (int base = 0; base < N; base += 1024) {
    int chunk = min(1024, N - base);
    __syncthreads();
    for (int j = d; j < chunk; j += 256) slab[j] = labels[base + j];
    __syncthreads();
    for (int j = 0; j < chunk; ++j) {
      if (slab[j] == c) {
        acc += F[(size_t)(base + j) * D + d];
        cnt++;
      }
    }
  }
  float fcnt = (float)cnt;
  float ave = acc / fmaxf(fcnt, 1.0f);
  float denom = fcnt + Amount[c];
  float w = (denom > 0.0f) ? (fcnt / denom) : 0.0f;
  float anew = Ave[c * D + d] * (1.0f - w) + ave * w;

  red[d] = anew * anew;
  __syncthreads();
  for (int st = 128; st > 0; st >>= 1) {
    if (d < st) red[d] += red[d + st];
    __syncthreads();
  }
  float R2 = red[0];
  float R = sqrtf(R2);
  float kap = 256.0f * R / (1.0f - R2);
  if (kap > 100000.0f || kap < 0.0f) kap = 100000.0f;
  float mu = anew / fmaxf(R, 1e-12f);
  kmuT[(size_t)d * C + c] = kap * mu;

  if (d == 0) {
    float lr0 = log_ive_nu(kap);
    logc[c] = lr0 + kap - (float)NU * logf(kap + 1e-20f);
  }
}

// 4 rows per block, 512 threads: thread (r, c) owns entry (n0+r, c).
// kappa_new computed directly as || kmu_c + f_n/T || (matches reference op
// order); then the per-entry Bessel recurrence; then row log-softmax in LDS.
__global__ __launch_bounds__(512) void k_main(
    const float* __restrict__ F, const int* __restrict__ labels,
    const float* __restrict__ kmuT, const float* __restrict__ logc,
    int N, int C, float* __restrict__ rowloss) {
  __shared__ float fT[4][D];
  __shared__ float red[4][128];
  const int tid = threadIdx.x;
  const int r = tid >> 7;
  const int c = tid & 127;
  const int n0 = blockIdx.x * 4;

  // stage 4 feature rows, pre-scaled by 1/T = 10
  for (int idx = tid; idx < 4 * D; idx += 512) {
    int rr = idx >> 8, dd = idx & 255;
    int n = n0 + rr;
    fT[rr][dd] = (n < N) ? F[(size_t)n * D + dd] * 10.0f : 0.0f;
  }
  __syncthreads();

  const int n = n0 + r;
  float logit = -INFINITY;
  if (n < N && c < C) {
    float s = 0.0f;
    #pragma unroll 4
    for (int d = 0; d < D; ++d) {
      float t = kmuT[(size_t)d * C + c] + fT[r][d];
      s = fmaf(t, t, s);
    }
    float x = sqrtf(s);
    float lr0 = log_ive_nu(x);
    logit = lr0 + x - (float)NU * logf(x + 1e-20f) - logc[c];
  }

  // row max
  red[r][c] = logit;
  __syncthreads();
  for (int st = 64; st > 0; st >>= 1) {
    if (c < st) red[r][c] = fmaxf(red[r][c], red[r][c + st]);
    __syncthreads();
  }
  float mx = red[r][0];
  __syncthreads();

  // row sum of exp
  float e = (logit > -INFINITY) ? expf(logit - mx) : 0.0f;
  red[r][c] = e;
  __syncthreads();
  for (int st = 64; st > 0; st >>= 1) {
    if (c < st) red[r][c] += red[r][c + st];
    __syncthreads();
  }

  if (n < N) {
    float lse = mx + logf(red[r][0]);
    int lab = labels[n];
    if (c == lab) rowloss[n] = lse - logit;
  }
}

__global__ __launch_bounds__(256) void k_reduce(
    const float* __restrict__ rowloss, int N, float* __restrict__ out) {
  __shared__ float red[256];
  float s = 0.0f;
  for (int i = threadIdx.x; i < N; i += 256) s += rowloss[i];
  red[threadIdx.x] = s;
  __syncthreads();
  for (int st = 128; st > 0; st >>= 1) {
    if (threadIdx.x < st) red[threadIdx.x] += red[threadIdx.x + st];
    __syncthreads();
  }
  if (threadIdx.x == 0) out[0] = red[0] / (float)N;
}

extern "C" void kernel_launch(void* const* d_in, const int* in_sizes, int n_in,
                              void* d_out, int out_size, void* d_ws, size_t ws_size,
                              hipStream_t stream) {
  const float* F = (const float*)d_in[0];
  const float* Ave = (const float*)d_in[1];
  const float* Amount = (const float*)d_in[2];
  const int* labels = (const int*)d_in[3];
  const int N = in_sizes[0] / D;
  const int C = in_sizes[2];

  float* ws = (float*)d_ws;
  float* kmuT = ws;                        // D*C floats
  float* logc = kmuT + (size_t)D * C;      // C floats
  float* rowloss = logc + C;               // N floats

  k_stats<<<C, 256, 0, stream>>>(F, Ave, Amount, labels, N, C, kmuT, logc);

  const int ROWS = 4;
  const int nb = (N + ROWS - 1) / ROWS;
  k_main<<<nb, 512, 0, stream>>>(F, labels, kmuT, logc, N, C, rowloss);

  k_reduce<<<1, 256, 0, stream>>>(rowloss, N, (float*)d_out);
}

// Round 2
// 65.410 us; speedup vs baseline: 4.1606x; 4.1606x over previous
//
#include <hip/hip_runtime.h>
#include <math.h>

#define D 256
#define NU 127
#define LN2P64 44.3614195558365f  // ln(2^64)

// log(i0e(x)) via Abramowitz & Stegun 9.8.1 / 9.8.2 (|err| < 2e-7)
__device__ __forceinline__ float li0e_poly(float xc) {
  xc = fmaxf(xc, 1e-10f);
  if (xc >= 3.75f) {
    float t = 3.75f / xc;
    float P = 0.39894228f + t * (0.01328592f + t * (0.00225319f + t * (-0.00157565f +
              t * (0.00916281f + t * (-0.02057706f + t * (0.02635537f + t * (-0.01647633f +
              t * 0.00392377f)))))));
    return logf(P) - 0.5f * logf(xc);
  } else {
    float u = xc * (1.0f / 3.75f);
    u = u * u;
    float P = 1.0f + u * (3.5156229f + u * (3.0899424f + u * (1.2067492f +
              u * (0.2659732f + u * (0.0360768f + u * 0.0045813f)))));
    return logf(P) - xc;
  }
}

// TWO interleaved Miller downward recurrences (i = 254..1) in linear space.
// Rescale by exact 2^-64 checked every <=4 steps (scale-invariant ratio).
// Returns lr = log(p_127 / p_0) for each x, i.e. Lnu - L0 of the reference.
__device__ __forceinline__ void lratio2(float x0, float x1, float& lr0o, float& lr1o) {
  float rx0 = 1.0f / fmaxf(x0, 1e-10f);
  float rx1 = 1.0f / fmaxf(x1, 1e-10f);
  float a0 = 2.0f * rx0, a1 = 2.0f * rx1;
  float c0 = 508.0f * rx0, c1 = 508.0f * rx1;  // 2i/x starting at i=254
  float p0 = 1.0f, q0 = 0.0f, k0 = 0.0f;
  float p1 = 1.0f, q1 = 0.0f, k1 = 0.0f;
  float pn0, kn0, pn1, kn1;
#define ST { float t0 = fmaf(c0, p0, q0); float t1 = fmaf(c1, p1, q1); \
             c0 -= a0; c1 -= a1; q0 = p0; q1 = p1; p0 = t0; p1 = t1; }
#define RS { bool b0 = p0 > 0x1p64f; bool b1 = p1 > 0x1p64f; \
             float s0 = b0 ? 0x1p-64f : 1.0f; float s1 = b1 ? 0x1p-64f : 1.0f; \
             k0 += b0 ? 1.0f : 0.0f; k1 += b1 ? 1.0f : 0.0f; \
             p0 *= s0; q0 *= s0; p1 *= s1; q1 *= s1; }
  // phase A: i = 254..129 (126 steps)
  #pragma unroll 1
  for (int g = 0; g < 31; ++g) { ST ST ST ST RS }
  ST ST RS
  // i = 128: this step produces p_127 (reference's Lnu capture)
  ST
  pn0 = p0; kn0 = k0; pn1 = p1; kn1 = k1;
  // phase B: i = 127..1 (127 steps)
  #pragma unroll 1
  for (int g = 0; g < 31; ++g) { ST ST ST ST RS }
  ST ST ST RS
#undef ST
#undef RS
  lr0o = logf(pn0) - logf(p0) + (kn0 - k0) * LN2P64;
  lr1o = logf(pn1) - logf(p1) + (kn1 - k1) * LN2P64;
}

// One block per class. Parallel label scan: per-wave ballot compaction into a
// deterministic ordered LDS list of matching rows, then coalesced row sums.
__global__ __launch_bounds__(256) void k_stats(
    const float* __restrict__ F, const float* __restrict__ Ave,
    const float* __restrict__ Amount, const int* __restrict__ labels,
    int N, int C, float2* __restrict__ kmu2T, float* __restrict__ logc) {
  const int c = blockIdx.x;
  const int t = threadIdx.x;  // doubles as feature dim d in phase 2
  const int lane = t & 63, w = t >> 6;
  __shared__ int list[4096];
  __shared__ int wtmp[4];
  __shared__ float red[256];

  float acc = 0.0f;
  int cnt_total = 0;
  for (int sbase = 0; sbase < N; sbase += 4096) {
    const int send = min(N, sbase + 4096);
    int total = 0;
    for (int base = sbase; base < send; base += 256) {
      int row = base + t;
      bool m = (row < send) && (labels[row] == c);
      unsigned long long mask = __ballot(m);
      int before = __popcll(mask & ((1ULL << lane) - 1ULL));
      if (lane == 0) wtmp[w] = __popcll(mask);
      __syncthreads();
      int woff = 0;
      for (int i = 0; i < w; ++i) woff += wtmp[i];
      int chunk_total = wtmp[0] + wtmp[1] + wtmp[2] + wtmp[3];
      if (m) list[total + woff + before] = row;
      total += chunk_total;
      __syncthreads();
    }
    // list complete (trailing syncthreads above); accumulate matched rows
    int k = 0;
    for (; k + 4 <= total; k += 4) {
      int r0 = list[k], r1 = list[k + 1], r2 = list[k + 2], r3 = list[k + 3];
      float v0 = F[(size_t)r0 * D + t];
      float v1 = F[(size_t)r1 * D + t];
      float v2 = F[(size_t)r2 * D + t];
      float v3 = F[(size_t)r3 * D + t];
      acc += v0; acc += v1; acc += v2; acc += v3;
    }
    for (; k < total; ++k) acc += F[(size_t)list[k] * D + t];
    cnt_total += total;
    __syncthreads();  // protect list for next super-chunk
  }

  float fcnt = (float)cnt_total;
  float ave = acc / fmaxf(fcnt, 1.0f);
  float denom = fcnt + Amount[c];
  float wgt = (denom > 0.0f) ? (fcnt / denom) : 0.0f;
  float anew = Ave[c * D + t] * (1.0f - wgt) + ave * wgt;

  red[t] = anew * anew;
  __syncthreads();
  for (int st = 128; st > 0; st >>= 1) {
    if (t < st) red[t] += red[t + st];
    __syncthreads();
  }
  float R2 = red[0];
  float R = sqrtf(R2);
  float kap = 256.0f * R / (1.0f - R2);
  if (kap > 100000.0f || kap < 0.0f) kap = 100000.0f;
  float mu = anew / fmaxf(R, 1e-12f);
  float kmu = kap * mu;

  // kmu2T[d][lane] = {kmu[class=lane], kmu[class=lane+64]}
  if (c < 64) kmu2T[t * 64 + c].x = kmu;
  else        kmu2T[t * 64 + (c - 64)].y = kmu;

  // pad classes [C,128) with zeros so k_main reads finite garbage-free values
  if (c == 0) {
    for (int cc = C; cc < 128; ++cc) {
      if (cc < 64) kmu2T[t * 64 + cc].x = 0.0f;
      else         kmu2T[t * 64 + (cc - 64)].y = 0.0f;
    }
    if (t >= C && t < 128) logc[t] = 0.0f;
  }

  if (t == 0) {
    float lr, dummy;
    lratio2(kap, kap, lr, dummy);
    logc[c] = li0e_poly(kap) + lr + kap - (float)NU * logf(kap + 1e-20f);
  }
}

// 8 rows per 512-thread block; 64 lanes per row; lane owns classes (lane, lane+64).
// Dual interleaved Bessel recurrences per thread; wave-shuffle softmax.
__global__ __launch_bounds__(512) void k_main(
    const float* __restrict__ F, const int* __restrict__ labels,
    const float2* __restrict__ kmu2T, const float* __restrict__ logc,
    int N, int C, float* __restrict__ rowloss) {
  __shared__ float fT[8][D];
  const int tid = threadIdx.x;
  const int r = tid >> 6, lane = tid & 63;
  const int n0 = blockIdx.x * 8;

  // stage 8 feature rows (pre-scaled by 1/T = 10): 512 threads x 1 float4
  {
    int rr = tid >> 6;          // 64 float4s per row
    int dd = (tid & 63) << 2;
    int n = n0 + rr;
    float4 v = make_float4(0.f, 0.f, 0.f, 0.f);
    if (n < N) v = *(const float4*)&F[(size_t)n * D + dd];
    v.x *= 10.f; v.y *= 10.f; v.z *= 10.f; v.w *= 10.f;
    *(float4*)&fT[rr][dd] = v;
  }
  __syncthreads();

  const int n = n0 + r;
  float s0 = 0.0f, s1 = 0.0f;
  #pragma unroll 2
  for (int d = 0; d < D; d += 4) {
    float4 g = *(const float4*)&fT[r][d];
    float2 m0 = kmu2T[(d + 0) * 64 + lane];
    float2 m1 = kmu2T[(d + 1) * 64 + lane];
    float2 m2 = kmu2T[(d + 2) * 64 + lane];
    float2 m3 = kmu2T[(d + 3) * 64 + lane];
    float u;
    u = m0.x + g.x; s0 = fmaf(u, u, s0);  u = m0.y + g.x; s1 = fmaf(u, u, s1);
    u = m1.x + g.y; s0 = fmaf(u, u, s0);  u = m1.y + g.y; s1 = fmaf(u, u, s1);
    u = m2.x + g.z; s0 = fmaf(u, u, s0);  u = m2.y + g.z; s1 = fmaf(u, u, s1);
    u = m3.x + g.w; s0 = fmaf(u, u, s0);  u = m3.y + g.w; s1 = fmaf(u, u, s1);
  }
  float x0 = sqrtf(s0), x1 = sqrtf(s1);

  float lr0, lr1;
  lratio2(x0, x1, lr0, lr1);

  const int c0 = lane, c1 = lane + 64;
  float logit0 = li0e_poly(x0) + lr0 + x0 - (float)NU * logf(x0 + 1e-20f) - logc[c0];
  float logit1 = li0e_poly(x1) + lr1 + x1 - (float)NU * logf(x1 + 1e-20f) - logc[c1];
  if (c0 >= C) logit0 = -INFINITY;
  if (c1 >= C) logit1 = -INFINITY;

  // wave-level row max
  float mx = fmaxf(logit0, logit1);
  #pragma unroll
  for (int off = 32; off > 0; off >>= 1) mx = fmaxf(mx, __shfl_xor(mx, off, 64));

  // wave-level sum of exp
  float e = expf(logit0 - mx) + expf(logit1 - mx);  // exp(-inf)=0 handles pads
  #pragma unroll
  for (int off = 32; off > 0; off >>= 1) e += __shfl_xor(e, off, 64);

  if (n < N) {
    float lse = mx + logf(e);
    int lab = labels[n];
    if (lab == c0)      rowloss[n] = lse - logit0;
    else if (lab == c1) rowloss[n] = lse - logit1;
  }
}

__global__ __launch_bounds__(256) void k_reduce(
    const float* __restrict__ rowloss, int N, float* __restrict__ out) {
  __shared__ float red[256];
  float s = 0.0f;
  for (int i = threadIdx.x; i < N; i += 256) s += rowloss[i];
  red[threadIdx.x] = s;
  __syncthreads();
  for (int st = 128; st > 0; st >>= 1) {
    if (threadIdx.x < st) red[threadIdx.x] += red[threadIdx.x + st];
    __syncthreads();
  }
  if (threadIdx.x == 0) out[0] = red[0] / (float)N;
}

extern "C" void kernel_launch(void* const* d_in, const int* in_sizes, int n_in,
                              void* d_out, int out_size, void* d_ws, size_t ws_size,
                              hipStream_t stream) {
  const float* F = (const float*)d_in[0];
  const float* Ave = (const float*)d_in[1];
  const float* Amount = (const float*)d_in[2];
  const int* labels = (const int*)d_in[3];
  const int N = in_sizes[0] / D;
  const int C = in_sizes[2];

  float* ws = (float*)d_ws;
  float2* kmu2T = (float2*)ws;                     // D*64 float2 = D*128 floats
  float* logc = ws + (size_t)D * 128;              // 128 floats (padded)
  float* rowloss = logc + 128;                     // N floats

  k_stats<<<C, 256, 0, stream>>>(F, Ave, Amount, labels, N, C, kmu2T, logc);

  const int nb = (N + 7) / 8;
  k_main<<<nb, 512, 0, stream>>>(F, labels, kmu2T, logc, N, C, rowloss);

  k_reduce<<<1, 256, 0, stream>>>(rowloss, N, (float*)d_out);
}

// Round 3
// 37.289 us; speedup vs baseline: 7.2981x; 1.7541x over previous
//
#include <hip/hip_runtime.h>
#include <math.h>

#define D 256
#define NUF 127.0f
#define C_MAX 128
#define TN 16384
#define T0F (-4.0f)
#define T1F (16.75f)
#define DTF ((T1F - T0F) / (float)(TN - 1))
#define INVDTF ((float)(TN - 1) / (T1F - T0F))
#define LN2F 0.69314718056f
#define RSU 44.3614195558365f  // ln(2^64)

// Single-chain Miller downward recurrence (i = 254..1), linear space with
// 2^-64 rescale checked every P steps. Returns log(p_127 / p_0), identical
// truncation to the reference's log-space scan.
template<int P>
__device__ __forceinline__ float lratio1(float x) {
  float rx = 1.0f / fmaxf(x, 1e-10f);
  float a = 2.0f * rx;
  float cc = 508.0f * rx;  // 2i/x at i=254
  float p = 1.0f, q = 0.0f, k = 0.0f;
  // phase A: 127 steps (i = 254..128); the last step produces p_127
  #pragma unroll
  for (int s = 0; s < 127; ++s) {
    float tn = fmaf(cc, p, q);
    cc -= a; q = p; p = tn;
    if ((s % P) == P - 1 || s == 126) {
      bool b = p > 0x1p64f;
      float sc = b ? 0x1p-64f : 1.0f;
      p *= sc; q *= sc; k += b ? 1.0f : 0.0f;
    }
  }
  float pn = p, kn = k;
  // phase B: 127 steps (i = 127..1)
  #pragma unroll
  for (int s = 0; s < 127; ++s) {
    float tn = fmaf(cc, p, q);
    cc -= a; q = p; p = tn;
    if ((s % P) == P - 1) {
      bool b = p > 0x1p64f;
      float sc = b ? 0x1p-64f : 1.0f;
      p *= sc; q *= sc; k += b ? 1.0f : 0.0f;
    }
  }
  return logf(pn) - logf(p) + (kn - k) * RSU;
}

// log(i0e(x)) via A&S 9.8.1 / 9.8.2 (|err| < 2e-7); t2 = log2(x) for big path
__device__ __forceinline__ float li0e_f(float x, float t2) {
  if (x >= 3.75f) {
    float t = 3.75f / x;
    float P = 0.39894228f + t*(0.01328592f + t*(0.00225319f + t*(-0.00157565f +
              t*(0.00916281f + t*(-0.02057706f + t*(0.02635537f + t*(-0.01647633f +
              t*0.00392377f)))))));
    return logf(P) - 0.5f * LN2F * t2;
  } else {
    float u = x * (1.0f / 3.75f); u *= u;
    float P = 1.0f + u*(3.5156229f + u*(3.0899424f + u*(1.2067492f +
              u*(0.2659732f + u*(0.0360768f + u*0.0045813f)))));
    return logf(P) - x;
  }
}

// logit (without -logc) from s = x^2, via table-interpolated lr
__device__ __forceinline__ float logit_from(float s, const float* __restrict__ ltab) {
  float x = sqrtf(fmaxf(s, 1e-20f));
  float t2 = log2f(x);
  float fi = fminf(fmaxf((t2 - T0F) * INVDTF, 0.0f), (float)(TN - 1) - 0.001f);
  int i0 = (int)fi;
  float fr = fi - (float)i0;
  float l0 = ltab[i0], l1 = ltab[i0 + 1];
  float lr = fmaf(l1 - l0, fr, l0);
  return li0e_f(x, t2) + lr + x - NUF * (LN2F * t2);
}

// blocks [0,C): per-class stats -> m2 (=2*kappa*mu, tiled planar layout),
//               kap2, logc (direct per-class recurrence, P=1 rescale)
// blocks [C, C+32): build the 16384-entry lr table; block C also zero-pads
__global__ __launch_bounds__(512) void k_prep(
    const float* __restrict__ F, const float* __restrict__ Ave,
    const float* __restrict__ Amount, const int* __restrict__ labels,
    int N, int C, float* __restrict__ m2g, float* __restrict__ kap2,
    float* __restrict__ logc, float* __restrict__ ltab) {
  const int t = threadIdx.x;
  const int bid = blockIdx.x;
  if (bid >= C) {
    int i = (bid - C) * 512 + t;
    if (i < TN) {
      float x = exp2f(T0F + DTF * (float)i);
      ltab[i] = lratio1<4>(x);
    }
    if (bid == C && C < C_MAX) {
      int npad = C_MAX - C;
      for (int j = t; j < 256 * npad; j += 512) {
        int cpad = C + (j % npad);
        int rest = j / npad;  // 0..255: tile(2b) plane(1b) d2(5b)
        int d2 = rest & 31, plane = (rest >> 5) & 1, tile = rest >> 6;
        m2g[tile * 8192 + plane * 4096 + d2 * 128 + cpad] = 0.0f;
      }
      for (int j = t; j < npad; j += 512) { kap2[C + j] = 0.0f; logc[C + j] = 0.0f; }
    }
    return;
  }
  const int c = bid;
  const int lane = t & 63, w = t >> 6;
  __shared__ int list[4096];
  __shared__ int wcnt[8];
  __shared__ float red[512];

  // parallel ballot-compaction of matching row indices (deterministic order)
  int total = 0;
  for (int base = 0; base < N; base += 512) {
    int row = base + t;
    bool m = (row < N) && (labels[row] == c);
    unsigned long long mask = __ballot(m);
    if (lane == 0) wcnt[w] = __popcll(mask);
    int before = __popcll(mask & ((1ULL << lane) - 1ULL));
    __syncthreads();
    int woff = total;
    #pragma unroll
    for (int i = 0; i < 8; ++i) { int v = wcnt[i]; if (i < w) woff += v; total += v; }
    if (m) list[woff + before] = row;
    __syncthreads();
  }

  // two halves (512 threads) accumulate alternating list entries, coalesced
  const int d = t & 255, half = t >> 8;
  float acc = 0.0f;
  {
    int k = half;
    for (; k + 6 < total; k += 8) {
      int r0 = list[k], r1 = list[k + 2], r2 = list[k + 4], r3 = list[k + 6];
      float v0 = F[(size_t)r0 * D + d], v1 = F[(size_t)r1 * D + d];
      float v2 = F[(size_t)r2 * D + d], v3 = F[(size_t)r3 * D + d];
      acc += v0; acc += v1; acc += v2; acc += v3;
    }
    for (; k < total; k += 2) acc += F[(size_t)list[k] * D + d];
  }
  red[t] = acc;
  __syncthreads();
  float anew = 0.0f;
  float fcnt = (float)total;
  if (t < 256) {
    acc = red[t] + red[t + 256];
    float ave = acc / fmaxf(fcnt, 1.0f);
    float denom = fcnt + Amount[c];
    float wgt = (denom > 0.0f) ? (fcnt / denom) : 0.0f;
    anew = Ave[c * D + d] * (1.0f - wgt) + ave * wgt;
  }
  __syncthreads();
  red[t] = (t < 256) ? anew * anew : 0.0f;
  __syncthreads();
  for (int st = 256; st > 0; st >>= 1) {
    if (t < st) red[t] += red[t + st];
    __syncthreads();
  }
  float R2 = red[0];
  float R = sqrtf(R2);
  float kap = 256.0f * R / (1.0f - R2);
  if (kap > 100000.0f || kap < 0.0f) kap = 100000.0f;
  if (t < 256) {
    float mu = anew / fmaxf(R, 1e-12f);
    float m2v = 2.0f * kap * mu;
    int tile = d >> 6, plane = d & 1, d2 = (d >> 1) & 31;
    m2g[tile * 8192 + plane * 4096 + d2 * 128 + c] = m2v;
  }
  if (t == 0) {
    kap2[c] = kap * kap;
    float t2 = log2f(fmaxf(kap, 1e-10f));
    logc[c] = li0e_f(kap, t2) + lratio1<1>(kap) + kap - NUF * logf(kap + 1e-20f);
  }
}

// block = 8 rows x 128 classes (512 threads). s = kap2[c] + ||g||^2 + m2.g
// with m2 tiles staged in LDS; logits via table interp; fused row softmax
// and per-block partial loss.
__global__ __launch_bounds__(512) void k_dot(
    const float* __restrict__ F, const int* __restrict__ labels,
    const float* __restrict__ m2g, const float* __restrict__ kap2,
    const float* __restrict__ logc, const float* __restrict__ ltab,
    int N, int C, float* __restrict__ partials) {
  __shared__ float g[8][D];     // 8 KB, pre-scaled by 1/T = 10
  __shared__ float mt[8192];    // 32 KB: [plane][d2][c]
  __shared__ float sf[8];
  __shared__ int lab[8];
  __shared__ float redA[4][2][2];
  __shared__ float rowloss[8];
  const int t = threadIdx.x;
  const int c = t & 127, rq = t >> 7, half = (t >> 6) & 1, lane = t & 63;
  const int n0 = blockIdx.x * 8;

  { // stage g + per-row ||g||^2 + labels (one wave per row)
    int srow = t >> 6;
    int sd = (t & 63) << 2;
    int n = n0 + srow;
    float4 v = make_float4(0.f, 0.f, 0.f, 0.f);
    if (n < N) v = *(const float4*)&F[(size_t)n * D + sd];
    v.x *= 10.f; v.y *= 10.f; v.z *= 10.f; v.w *= 10.f;
    *(float4*)&g[srow][sd] = v;
    float ps = v.x * v.x + v.y * v.y + v.z * v.z + v.w * v.w;
    #pragma unroll
    for (int off = 32; off > 0; off >>= 1) ps += __shfl_xor(ps, off, 64);
    if (lane == 0) sf[srow] = ps;
    if (t < 8) { lab[t] = (n0 + t < N) ? labels[n0 + t] : -1; rowloss[t] = 0.0f; }
  }

  float s0 = 0.f, s1 = 0.f;
  const int r0 = rq * 2, r1 = r0 + 1;
  for (int tile = 0; tile < 4; ++tile) {
    __syncthreads();
    #pragma unroll
    for (int p = 0; p < 4; ++p) {
      int idx = p * 2048 + t * 4;
      float4 mv = *(const float4*)&m2g[tile * 8192 + idx];
      *(float4*)&mt[idx] = mv;
    }
    __syncthreads();
    const float* mA = mt;         // d even
    const float* mB = mt + 4096;  // d odd
    #pragma unroll
    for (int d2 = 0; d2 < 32; d2 += 2) {
      int dd = tile * 64 + d2 * 2;
      float a0 = mA[d2 * 128 + c];
      float b0 = mB[d2 * 128 + c];
      float a1 = mA[(d2 + 1) * 128 + c];
      float b1 = mB[(d2 + 1) * 128 + c];
      float4 gA = *(const float4*)&g[r0][dd];
      float4 gB = *(const float4*)&g[r1][dd];
      s0 = fmaf(a0, gA.x, s0); s0 = fmaf(b0, gA.y, s0);
      s0 = fmaf(a1, gA.z, s0); s0 = fmaf(b1, gA.w, s0);
      s1 = fmaf(a0, gB.x, s1); s1 = fmaf(b0, gB.y, s1);
      s1 = fmaf(a1, gB.z, s1); s1 = fmaf(b1, gB.w, s1);
    }
  }

  __syncthreads();
  float kk = kap2[c], lgc = logc[c];
  float lg0 = logit_from(s0 + kk + sf[r0], ltab) - lgc;
  float lg1 = logit_from(s1 + kk + sf[r1], ltab) - lgc;
  if (c >= C) { lg0 = -INFINITY; lg1 = -INFINITY; }

  // row max across 128 class-threads (intra-wave shuffle + cross-wave LDS)
  float m0 = lg0, m1 = lg1;
  #pragma unroll
  for (int off = 32; off > 0; off >>= 1) {
    m0 = fmaxf(m0, __shfl_xor(m0, off, 64));
    m1 = fmaxf(m1, __shfl_xor(m1, off, 64));
  }
  if (lane == 0) { redA[rq][0][half] = m0; redA[rq][1][half] = m1; }
  __syncthreads();
  m0 = fmaxf(redA[rq][0][0], redA[rq][0][1]);
  m1 = fmaxf(redA[rq][1][0], redA[rq][1][1]);

  float e0 = expf(lg0 - m0);  // exp(-inf) = 0 handles padding
  float e1 = expf(lg1 - m1);
  #pragma unroll
  for (int off = 32; off > 0; off >>= 1) {
    e0 += __shfl_xor(e0, off, 64);
    e1 += __shfl_xor(e1, off, 64);
  }
  __syncthreads();  // all rq-groups done reading maxes before reuse
  if (lane == 0) { redA[rq][0][half] = e0; redA[rq][1][half] = e1; }
  __syncthreads();
  float sum0 = redA[rq][0][0] + redA[rq][0][1];
  float sum1 = redA[rq][1][0] + redA[rq][1][1];
  float lse0 = m0 + logf(sum0);
  float lse1 = m1 + logf(sum1);
  if (c == lab[r0]) rowloss[r0] = lse0 - lg0;
  if (c == lab[r1]) rowloss[r1] = lse1 - lg1;
  __syncthreads();
  if (t == 0) {
    float a = 0.f;
    #pragma unroll
    for (int j = 0; j < 8; ++j) a += rowloss[j];
    partials[blockIdx.x] = a;
  }
}

__global__ __launch_bounds__(512) void k_reduce(
    const float* __restrict__ partials, int nb, int N, float* __restrict__ out) {
  __shared__ float red[512];
  float a = 0.f;
  for (int i = threadIdx.x; i < nb; i += 512) a += partials[i];
  red[threadIdx.x] = a;
  __syncthreads();
  for (int st = 256; st > 0; st >>= 1) {
    if (threadIdx.x < st) red[threadIdx.x] += red[threadIdx.x + st];
    __syncthreads();
  }
  if (threadIdx.x == 0) out[0] = red[0] / (float)N;
}

extern "C" void kernel_launch(void* const* d_in, const int* in_sizes, int n_in,
                              void* d_out, int out_size, void* d_ws, size_t ws_size,
                              hipStream_t stream) {
  const float* F = (const float*)d_in[0];
  const float* Ave = (const float*)d_in[1];
  const float* Amount = (const float*)d_in[2];
  const int* labels = (const int*)d_in[3];
  const int N = in_sizes[0] / D;
  const int C = in_sizes[2];

  float* ws = (float*)d_ws;
  float* m2g = ws;               // 4*2*32*128 = 32768 floats
  float* kap2 = ws + 32768;      // 128
  float* logc = ws + 32896;      // 128
  float* ltab = ws + 33024;      // 16384
  float* partials = ws + 49408;  // nb

  const int tb = (TN + 511) / 512;  // 32 table blocks
  k_prep<<<C + tb, 512, 0, stream>>>(F, Ave, Amount, labels, N, C, m2g, kap2, logc, ltab);

  const int nb = (N + 7) / 8;
  k_dot<<<nb, 512, 0, stream>>>(F, labels, m2g, kap2, logc, ltab, N, C, partials);

  k_reduce<<<1, 512, 0, stream>>>(partials, nb, N, (float*)d_out);
}